// Round 4
// baseline (260.470 us; speedup 1.0000x reference)
//
#include <hip/hip_runtime.h>
#include <math.h>

#define DIMS   256
#define KCODES 1024
#define NTOT   32768
#define TAU    0.002f

typedef __bf16 bf16x8 __attribute__((ext_vector_type(8)));
typedef float  f32x4  __attribute__((ext_vector_type(4)));

typedef const void __attribute__((address_space(1))) glb_cv;
typedef void __attribute__((address_space(3))) lds_v;

__device__ __forceinline__ void gload_lds16(const void* g, void* l) {
  __builtin_amdgcn_global_load_lds((glb_cv*)g, (lds_v*)l, 16, 0, 0);
}

// ---- workspace layout (float indices; int views share) ----
#define WS_COMMIT   0          // float atomic
#define WS_FLAGCNT  1          // int atomic
#define WS_DECORR   2          // float atomic
#define WS_COLSUM   16         // float[256]
#define WS_COLSQ    272        // float[256]
// zero region: first 2112 bytes
#define WS_WSQ      1024       // float[1024]
#define WS_XSQ      2048       // float[32768]
#define WS_FLAGS    34816      // int[32768]
#define WS_CAND1    67584      // float[8*32768]
#define WS_CAND2    329728     // float[8*32768]
#define WS_CANDI    591872     // int[8*32768]
#define WS_WP       854016     // bf16[1024*256*2] = 1 MB

// ---- output layout (floats) ----
#define OUT_Q    0
#define OUT_IDX  8388608
#define OUT_SCAL 8421376

// ---------- pack fp32 -> swizzled hi/lo bf16 tiles + row sumsq ----------
// Tile layout (bf16 elems): [(rb*8+kt)*8192 + row128*64 + p*8 + e]
// slot p holds logical s = p ^ (row&7); s<4: hi of k-group s; s>=4: lo of k-group s-4.
__global__ __launch_bounds__(256) void pack_kernel(const float* __restrict__ src,
                                                   __bf16* __restrict__ dst,
                                                   float* __restrict__ sqOut) {
  int tid = threadIdx.x;
  int row = blockIdx.x * 64 + (tid >> 2);
  int kg = tid & 3;
  int rb = row >> 7, rl = row & 127;
  int p1 = kg ^ (rl & 7);
  float sq = 0.f;
  #pragma unroll
  for (int kt = 0; kt < 8; kt++) {
    const float* s = src + (size_t)row * DIMS + kt * 32 + kg * 8;
    float4 u = *(const float4*)s;
    float4 v = *(const float4*)(s + 4);
    float f[8] = {u.x, u.y, u.z, u.w, v.x, v.y, v.z, v.w};
    bf16x8 hi, lo;
    #pragma unroll
    for (int e = 0; e < 8; e++) {
      __bf16 h = (__bf16)f[e];
      hi[e] = h;
      lo[e] = (__bf16)(f[e] - (float)h);
      sq = fmaf(f[e], f[e], sq);
    }
    size_t base = ((size_t)(rb * 8 + kt) * 128 + rl) * 64;
    *(bf16x8*)&dst[base + p1 * 8] = hi;
    *(bf16x8*)&dst[base + (p1 ^ 4) * 8] = lo;
  }
  sq += __shfl_xor(sq, 1);
  sq += __shfl_xor(sq, 2);
  if (kg == 0) sqOut[row] = sq;
}

// ---------- per-column sum / sumsq of W ----------
__global__ __launch_bounds__(256) void colstats_kernel(const float* __restrict__ W, float* ws) {
  int d = threadIdx.x;
  int r0 = blockIdx.x * 32;
  float s = 0.f, sq = 0.f;
  #pragma unroll 8
  for (int k = 0; k < 32; k++) {
    float v = W[(size_t)(r0 + k) * DIMS + d];
    s += v;
    sq = fmaf(v, v, sq);
  }
  atomicAdd(&ws[WS_COLSUM + d], s);
  atomicAdd(&ws[WS_COLSQ + d], sq);
}

// ---------- pass1: DMA-staged, double-buffered bf16-split MFMA distance GEMM ----------
// 1D grid 2048, XCD-swizzled: bm=(l&7)*32+((l>>3)&31), bn=l>>8.
// LDS: A bufs @0/16K, B bufs @32K/48K; epilogue arrays alias A-buf0.
__global__ __launch_bounds__(256) void pass1_kernel(const __bf16* __restrict__ Xp,
                                                    const __bf16* __restrict__ Wp,
                                                    float* ws) {
  __shared__ __align__(16) char smem[65536];
  __shared__ float wsqs[128];
  float* d1L = (float*)smem;           // 256 floats (aliases A-buf0, used post-loop)
  float* d2L = (float*)(smem + 1024);
  int*   i1L = (int*)(smem + 2048);

  int tid = threadIdx.x;
  int lane = tid & 63, wave = tid >> 6;
  int waveM = wave >> 1, waveN = wave & 1;
  int quad = lane >> 4, col = lane & 15;
  int l = blockIdx.x;
  int bm = (l & 7) * 32 + ((l >> 3) & 31);
  int bn = l >> 8;
  int rowBase = bm * 128, cb = bn * 128;

  if (tid < 128) wsqs[tid] = ws[WS_WSQ + cb + tid];

  f32x4 acc[4][4];
  #pragma unroll
  for (int i = 0; i < 4; i++)
    #pragma unroll
    for (int j = 0; j < 4; j++) acc[i][j] = (f32x4){0.f, 0.f, 0.f, 0.f};

  const char* abase = (const char*)(Xp + ((size_t)(bm * 8) << 13));
  const char* bbase = (const char*)(Wp + ((size_t)(bn * 8) << 13));
  int llo = wave * 4096 + lane * 16;

  // prefetch kt=0 into buf0
  #pragma unroll
  for (int i = 0; i < 4; i++) {
    int off = wave * 4096 + i * 1024;
    gload_lds16(abase + off + lane * 16, smem + off);
    gload_lds16(bbase + off + lane * 16, smem + 32768 + off);
  }
  (void)llo;

  for (int kt = 0; kt < 8; kt++) {
    __syncthreads();  // drains DMA for buf[kt&1]; guards buf[(kt+1)&1] reuse
    if (kt < 7) {
      int b = (kt + 1) & 1;
      const char* as = abase + (size_t)(kt + 1) * 16384;
      const char* bs = bbase + (size_t)(kt + 1) * 16384;
      #pragma unroll
      for (int i = 0; i < 4; i++) {
        int off = wave * 4096 + i * 1024;
        gload_lds16(as + off + lane * 16, smem + b * 16384 + off);
        gload_lds16(bs + off + lane * 16, smem + 32768 + b * 16384 + off);
      }
    }
    const __bf16* Ab = (const __bf16*)(smem + (kt & 1) * 16384);
    const __bf16* Bb = (const __bf16*)(smem + 32768 + (kt & 1) * 16384);

    bf16x8 ah[4], al[4];
    #pragma unroll
    for (int mt = 0; mt < 4; mt++) {
      int r = waveM * 64 + mt * 16 + col;
      int ph = quad ^ (r & 7);
      ah[mt] = *(const bf16x8*)&Ab[r * 64 + ph * 8];
      al[mt] = *(const bf16x8*)&Ab[r * 64 + (ph ^ 4) * 8];
    }
    #pragma unroll
    for (int nt = 0; nt < 4; nt++) {
      int r = waveN * 64 + nt * 16 + col;
      int ph = quad ^ (r & 7);
      bf16x8 bh = *(const bf16x8*)&Bb[r * 64 + ph * 8];
      bf16x8 bl = *(const bf16x8*)&Bb[r * 64 + (ph ^ 4) * 8];
      #pragma unroll
      for (int mt = 0; mt < 4; mt++) {
        acc[mt][nt] = __builtin_amdgcn_mfma_f32_16x16x32_bf16(ah[mt], bh, acc[mt][nt], 0, 0, 0);
        acc[mt][nt] = __builtin_amdgcn_mfma_f32_16x16x32_bf16(ah[mt], bl, acc[mt][nt], 0, 0, 0);
        acc[mt][nt] = __builtin_amdgcn_mfma_f32_16x16x32_bf16(al[mt], bh, acc[mt][nt], 0, 0, 0);
      }
    }
  }

  // epilogue: per-row (best, 2nd, idx) over this block's 128 codes
  // C layout: row = quad*4 + reg, col = lane&15
  #pragma unroll
  for (int mt = 0; mt < 4; mt++) {
    #pragma unroll
    for (int r = 0; r < 4; r++) {
      float d1 = 3.0e38f, d2 = 3.0e38f;
      int i1 = 0;
      #pragma unroll
      for (int nt = 0; nt < 4; nt++) {
        int lc = waveN * 64 + nt * 16 + col;
        float d = wsqs[lc] - 2.0f * acc[mt][nt][r];
        int g = cb + lc;
        if (d < d1) { d2 = d1; d1 = d; i1 = g; }
        else if (d < d2) d2 = d;
      }
      #pragma unroll
      for (int m = 1; m < 16; m <<= 1) {
        float od1 = __shfl_xor(d1, m);
        int oi1 = __shfl_xor(i1, m);
        float od2 = __shfl_xor(d2, m);
        if (od1 < d1 || (od1 == d1 && oi1 < i1)) {
          d2 = fminf(d1, fminf(d2, od2));
          d1 = od1; i1 = oi1;
        } else {
          d2 = fminf(od1, fminf(d2, od2));
        }
      }
      if (col == 0) {
        int lr = waveM * 64 + mt * 16 + quad * 4 + r;
        d1L[lr * 2 + waveN] = d1;
        d2L[lr * 2 + waveN] = d2;
        i1L[lr * 2 + waveN] = i1;
      }
    }
  }
  __syncthreads();
  if (tid < 128) {
    float a1 = d1L[tid * 2], a2 = d2L[tid * 2];
    int ai = i1L[tid * 2];
    float b1 = d1L[tid * 2 + 1], b2 = d2L[tid * 2 + 1];
    int bi = i1L[tid * 2 + 1];
    float m1, m2; int mi;
    if (b1 < a1 || (b1 == a1 && bi < ai)) { m1 = b1; mi = bi; m2 = fminf(a1, b2); }
    else { m1 = a1; mi = ai; m2 = fminf(b1, a2); }
    int o = bn * NTOT + rowBase + tid;
    ws[WS_CAND1 + o] = m1;
    ws[WS_CAND2 + o] = m2;
    ((int*)ws)[WS_CANDI + o] = mi;
  }
}

// ---------- pass2: merge candidates; idx, commit, flags; fused quant gather ----------
__global__ __launch_bounds__(256) void pass2_kernel(const float* __restrict__ W,
                                                    float* __restrict__ outQ,
                                                    float* __restrict__ outIdx, float* ws) {
  __shared__ int idx_s[256];
  int tid = threadIdx.x;
  int row = blockIdx.x * 256 + tid;
  const float* c1 = ws + WS_CAND1;
  const float* c2 = ws + WS_CAND2;
  const int* ci = (const int*)ws + WS_CANDI;
  float m1 = 3.0e38f, m2 = 3.0e38f;
  int mi = 0;
  #pragma unroll
  for (int b = 0; b < 8; b++) {
    int o = b * NTOT + row;
    float b1 = c1[o], b2 = c2[o];
    int bi = ci[o];
    if (b1 < m1 || (b1 == m1 && bi < mi)) { m2 = fminf(m1, b2); m1 = b1; mi = bi; }
    else { m2 = fminf(m2, b1); }
  }
  outIdx[row] = (float)mi;
  idx_s[tid] = mi;
  int* wsI = (int*)ws;
  if (m2 - m1 < TAU) {
    int p = atomicAdd(&wsI[WS_FLAGCNT], 1);
    wsI[WS_FLAGS + p] = row;
  }
  float partial = ws[WS_XSQ + row] + m1;
  #pragma unroll
  for (int m = 32; m >= 1; m >>= 1) partial += __shfl_xor(partial, m);
  if ((tid & 63) == 0) atomicAdd(&ws[WS_COMMIT], partial);
  __syncthreads();
  int wave = tid >> 6, lane = tid & 63;
  int rowBase = blockIdx.x * 256;
  for (int i = 0; i < 64; i++) {
    int rl = wave * 64 + i;
    int ix = idx_s[rl];
    float4 v = ((const float4*)(W + (size_t)ix * DIMS))[lane];
    ((float4*)(outQ + (size_t)(rowBase + rl) * DIMS))[lane] = v;
  }
}

// ---------- decorrelation: 64 blocks x 4 output rows ----------
__global__ __launch_bounds__(256) void cov_kernel(const float* __restrict__ W, float* ws) {
  __shared__ float wi_s[4][KCODES];
  __shared__ float red[4];
  int tid = threadIdx.x;
  int i0 = blockIdx.x * 4;
  int rr = tid >> 2, c = tid & 3;
  #pragma unroll
  for (int b = 0; b < 16; b++) {
    int row = b * 64 + rr;
    wi_s[c][row] = W[(size_t)row * DIMS + i0 + c];
  }
  __syncthreads();
  int j = tid;
  float a0 = 0.f, a1 = 0.f, a2 = 0.f, a3 = 0.f;
  for (int k = 0; k < KCODES; k += 4) {
    #pragma unroll
    for (int u = 0; u < 4; u++) {
      float wj = W[(size_t)(k + u) * DIMS + j];
      a0 = fmaf(wi_s[0][k + u], wj, a0);
      a1 = fmaf(wi_s[1][k + u], wj, a1);
      a2 = fmaf(wi_s[2][k + u], wj, a2);
      a3 = fmaf(wi_s[3][k + u], wj, a3);
    }
  }
  const float inv = 1.0f / 1024.0f;
  float mj = ws[WS_COLSUM + j] * inv;
  float dots[4] = {a0, a1, a2, a3};
  float v = 0.f;
  #pragma unroll
  for (int r = 0; r < 4; r++) {
    float mi = ws[WS_COLSUM + i0 + r] * inv;
    float cc = dots[r] * inv - mi * mj;
    if (i0 + r != j) v = fmaf(cc, cc, v);
  }
  #pragma unroll
  for (int m = 32; m >= 1; m >>= 1) v += __shfl_xor(v, m);
  if ((j & 63) == 0) red[j >> 6] = v;
  __syncthreads();
  if (j == 0) atomicAdd(&ws[WS_DECORR], (red[0] + red[1]) + (red[2] + red[3]));
}

// ---------- f64 refinement of near-tie rows ----------
__global__ __launch_bounds__(256) void refine_kernel(const float* __restrict__ X,
                                                     const float* __restrict__ W,
                                                     float* __restrict__ outQ,
                                                     float* __restrict__ outIdx, float* ws) {
  __shared__ float xs[DIMS];
  __shared__ double dm[256];
  __shared__ int im[256];
  __shared__ int chosen;
  const int* wsI = (const int*)ws;
  int cnt = wsI[WS_FLAGCNT];
  const int* list = wsI + WS_FLAGS;
  int tid = threadIdx.x;
  for (int f = blockIdx.x; f < cnt; f += gridDim.x) {
    int row = list[f];
    __syncthreads();
    if (tid < 64) ((float4*)xs)[tid] = ((const float4*)(X + (size_t)row * DIMS))[tid];
    __syncthreads();
    double bd = 1.0e300;
    int bi = 0;
    for (int jj = 0; jj < 4; jj++) {
      int c = tid + 256 * jj;
      double a0 = 0.0, a1 = 0.0, a2 = 0.0, a3 = 0.0;
      const float* wr = W + (size_t)c * DIMS;
      #pragma unroll 4
      for (int d4 = 0; d4 < 64; d4++) {
        float4 w = ((const float4*)wr)[d4];
        float4 x = ((const float4*)xs)[d4];
        double e0 = (double)x.x - (double)w.x;
        double e1 = (double)x.y - (double)w.y;
        double e2 = (double)x.z - (double)w.z;
        double e3 = (double)x.w - (double)w.w;
        a0 += e0 * e0; a1 += e1 * e1; a2 += e2 * e2; a3 += e3 * e3;
      }
      double s = (a0 + a1) + (a2 + a3);
      if (s < bd) { bd = s; bi = c; }
    }
    dm[tid] = bd; im[tid] = bi;
    __syncthreads();
    for (int st = 128; st >= 1; st >>= 1) {
      if (tid < st) {
        if (dm[tid + st] < dm[tid] || (dm[tid + st] == dm[tid] && im[tid + st] < im[tid])) {
          dm[tid] = dm[tid + st]; im[tid] = im[tid + st];
        }
      }
      __syncthreads();
    }
    if (tid == 0) { chosen = im[0]; outIdx[row] = (float)im[0]; }
    __syncthreads();
    int ix = chosen;
    if (tid < 64)
      ((float4*)(outQ + (size_t)row * DIMS))[tid] = ((const float4*)(W + (size_t)ix * DIMS))[tid];
  }
}

// ---------- scalar losses ----------
__global__ __launch_bounds__(256) void finalize_kernel(const float* __restrict__ U, float* ws,
                                                       float* __restrict__ out) {
  __shared__ float red[256];
  int tid = threadIdx.x;
  float s = 0.f;
  for (int e = tid; e < KCODES; e += 256) s += U[e] + 1e-5f;
  red[tid] = s;
  __syncthreads();
  for (int st = 128; st >= 1; st >>= 1) {
    if (tid < st) red[tid] += red[tid + st];
    __syncthreads();
  }
  float S = red[0];
  __syncthreads();
  float denom = fmaxf(S, 1e-5f * 1024.0f);
  float h = 0.f;
  for (int e = tid; e < KCODES; e += 256) {
    float p = (U[e] + 1e-5f) / denom;
    h += p * logf(p + 1e-5f);
  }
  red[tid] = h;
  __syncthreads();
  for (int st = 128; st >= 1; st >>= 1) {
    if (tid < st) red[tid] += red[tid + st];
    __syncthreads();
  }
  float H = -red[0] / 6.93147180559945f;  // ln(1024)
  __syncthreads();
  float m = ws[WS_COLSUM + tid] * (1.0f / 1024.0f);
  float var = ws[WS_COLSQ + tid] * (1.0f / 1024.0f) - m * m;
  float r = 0.05f - var;
  red[tid] = r > 0.f ? r : 0.f;
  __syncthreads();
  for (int st = 128; st >= 1; st >>= 1) {
    if (tid < st) red[tid] += red[tid + st];
    __syncthreads();
  }
  if (tid == 0) {
    float varloss = 1e-3f * (red[0] / 256.0f);
    float gap = H < 0.5f ? (0.5f - H) : (H > 0.9f ? (H - 0.9f) : 0.0f);
    float entloss = 0.1f * gap * gap;
    float commit = 0.25f * ws[WS_COMMIT] / 8388608.0f;
    float dec = 1e-3f * ws[WS_DECORR] / 65536.0f;
    float* sc = out + OUT_SCAL;
    sc[0] = commit + entloss + varloss + dec;
    sc[1] = commit;
    sc[2] = entloss;
    sc[3] = varloss;
    sc[4] = dec;
    sc[5] = H;
  }
}

extern "C" void kernel_launch(void* const* d_in, const int* in_sizes, int n_in, void* d_out,
                              int out_size, void* d_ws, size_t ws_size, hipStream_t stream) {
  const float* X = (const float*)d_in[0];
  const float* W = (const float*)d_in[1];
  const float* U = (const float*)d_in[2];
  float* out = (float*)d_out;
  float* ws = (float*)d_ws;
  __bf16* Xp = (__bf16*)(out + OUT_Q);       // 33.55 MB, reused before gather overwrites
  __bf16* Wp = (__bf16*)(ws + WS_WP);        // 1 MB

  hipMemsetAsync(d_ws, 0, 2112, stream);
  pack_kernel<<<NTOT / 64, 256, 0, stream>>>(X, Xp, ws + WS_XSQ);
  pack_kernel<<<KCODES / 64, 256, 0, stream>>>(W, Wp, ws + WS_WSQ);
  colstats_kernel<<<32, 256, 0, stream>>>(W, ws);
  pass1_kernel<<<2048, 256, 0, stream>>>(Xp, Wp, ws);
  pass2_kernel<<<NTOT / 256, 256, 0, stream>>>(W, out + OUT_Q, out + OUT_IDX, ws);
  cov_kernel<<<64, 256, 0, stream>>>(W, ws);
  refine_kernel<<<512, 256, 0, stream>>>(X, W, out + OUT_Q, out + OUT_IDX, ws);
  finalize_kernel<<<1, 256, 0, stream>>>(U, ws, out);
}

// Round 5
// 246.162 us; speedup vs baseline: 1.0581x; 1.0581x over previous
//
#include <hip/hip_runtime.h>
#include <math.h>

#define DIMS   256
#define KCODES 1024
#define NTOT   32768
#define TAU    4.0e-4f   // 3-term split distance-compare error <~6e-5; 6x margin

typedef __bf16 bf16x8 __attribute__((ext_vector_type(8)));
typedef float  f32x4  __attribute__((ext_vector_type(4)));

typedef const void __attribute__((address_space(1))) glb_cv;
typedef void __attribute__((address_space(3))) lds_v;

__device__ __forceinline__ void gload_lds16(const void* g, void* l) {
  __builtin_amdgcn_global_load_lds((glb_cv*)g, (lds_v*)l, 16, 0, 0);
}

// ---- workspace layout (float indices; int views share) ----
#define WS_COMMIT   0          // float atomic
#define WS_FLAGCNT  1          // int atomic
#define WS_DECORR   2          // float atomic
#define WS_COLSUM   16         // float[256]
#define WS_COLSQ    272        // float[256]
// zero region: first 2112 bytes
#define WS_WSQ      1024       // float[1024]
#define WS_XSQ      2048       // float[32768]
#define WS_FLAGS    34816      // int[32768]
#define WS_CAND1    67584      // float[8*32768]
#define WS_CAND2    329728     // float[8*32768]
#define WS_CANDI    591872     // int[8*32768]
#define WS_WP       854016     // bf16[524288] = 1 MB, fragment-ordered W

// ---- output layout (floats) ----
#define OUT_Q    0
#define OUT_IDX  8388608
#define OUT_SCAL 8421376

// ---------- fused prep: packX (512 blocks) | packW-frag (32) | colstats (8) ----------
// Xp tile layout (bf16): [(rb*8+kt)*8192 + rl*64 + p*8 + e], slot p = s ^ (rl&7),
//   s<4: hi of k-group s; s>=4: lo of k-group s-4.
// Wp2 frag layout (bf16): frag(bn,kt,wn,nt,hl) at ((((bn*8+kt)*2+wn)*4+nt)*2+hl)*512,
//   within frag: lane (kq*16+lcol) holds 8 bf16 of k=kq*8+e for code col lcol.
__global__ __launch_bounds__(256) void prep_kernel(const float* __restrict__ X,
                                                   const float* __restrict__ W,
                                                   __bf16* __restrict__ Xp,
                                                   __bf16* __restrict__ Wp2,
                                                   float* ws) {
  int b = blockIdx.x;
  int tid = threadIdx.x;
  if (b < 512) {
    // ---- pack X ----
    int row = b * 64 + (tid >> 2);
    int kg = tid & 3;
    int rb = row >> 7, rl = row & 127;
    int p1 = kg ^ (rl & 7);
    float sq = 0.f;
    #pragma unroll
    for (int kt = 0; kt < 8; kt++) {
      const float* s = X + (size_t)row * DIMS + kt * 32 + kg * 8;
      float4 u = *(const float4*)s;
      float4 v = *(const float4*)(s + 4);
      float f[8] = {u.x, u.y, u.z, u.w, v.x, v.y, v.z, v.w};
      bf16x8 hi, lo;
      #pragma unroll
      for (int e = 0; e < 8; e++) {
        __bf16 h = (__bf16)f[e];
        hi[e] = h;
        lo[e] = (__bf16)(f[e] - (float)h);
        sq = fmaf(f[e], f[e], sq);
      }
      size_t base = ((size_t)(rb * 8 + kt) * 128 + rl) * 64;
      *(bf16x8*)&Xp[base + p1 * 8] = hi;
      *(bf16x8*)&Xp[base + (p1 ^ 4) * 8] = lo;
    }
    sq += __shfl_xor(sq, 1);
    sq += __shfl_xor(sq, 2);
    if (kg == 0) ws[WS_XSQ + row] = sq;
  } else if (b < 544) {
    // ---- pack W into fragment order + wsq ----
    int b2 = b - 512;
    int g = b2 * 32 + (tid >> 3);   // code row 0..1023
    int kt = tid & 7;
    int bn = g >> 7, c = g & 127;
    int wn = c >> 6, nt = (c >> 4) & 3, lcol = c & 15;
    size_t hibase = ((((size_t)(bn * 8 + kt) * 2 + wn) * 4 + nt) * 2 + 0) * 512;
    size_t lobase = hibase + 512;
    const float* s = W + (size_t)g * DIMS + kt * 32;
    float sq = 0.f;
    #pragma unroll
    for (int kq = 0; kq < 4; kq++) {
      float4 u = *(const float4*)(s + kq * 8);
      float4 v = *(const float4*)(s + kq * 8 + 4);
      float f[8] = {u.x, u.y, u.z, u.w, v.x, v.y, v.z, v.w};
      bf16x8 hi, lo;
      #pragma unroll
      for (int e = 0; e < 8; e++) {
        __bf16 h = (__bf16)f[e];
        hi[e] = h;
        lo[e] = (__bf16)(f[e] - (float)h);
        sq = fmaf(f[e], f[e], sq);
      }
      size_t off = (size_t)(kq * 16 + lcol) * 8;
      *(bf16x8*)&Wp2[hibase + off] = hi;
      *(bf16x8*)&Wp2[lobase + off] = lo;
    }
    sq += __shfl_xor(sq, 1);
    sq += __shfl_xor(sq, 2);
    sq += __shfl_xor(sq, 4);
    if (kt == 0) ws[WS_WSQ + g] = sq;
  } else {
    // ---- colstats: 8 blocks x 128 rows ----
    int d = tid;
    int r0 = (b - 544) * 128;
    float s = 0.f, sq = 0.f;
    #pragma unroll 8
    for (int k = 0; k < 128; k++) {
      float v = W[(size_t)(r0 + k) * DIMS + d];
      s += v;
      sq = fmaf(v, v, sq);
    }
    atomicAdd(&ws[WS_COLSUM + d], s);
    atomicAdd(&ws[WS_COLSQ + d], sq);
  }
}

// ---------- pass1: A via DMA'd LDS dbuf, B direct fragment loads, 3-term bf16 MFMA ----------
// 1D grid 2048, XCD-swizzled: bm=(l&7)*32+((l>>3)&31), bn=l>>8.
__global__ __launch_bounds__(256, 3) void pass1_kernel(const __bf16* __restrict__ Xp,
                                                       const __bf16* __restrict__ Wp2,
                                                       float* ws) {
  __shared__ __align__(16) char asmem[32768];   // A dbuf 2x16KB
  __shared__ float wsqs[128];
  __shared__ float d1L[256];
  __shared__ float d2L[256];
  __shared__ int   i1L[256];

  int tid = threadIdx.x;
  int lane = tid & 63, wave = tid >> 6;
  int waveM = wave >> 1, waveN = wave & 1;
  int quad = lane >> 4, col = lane & 15;
  int l = blockIdx.x;
  int bm = (l & 7) * 32 + ((l >> 3) & 31);
  int bn = l >> 8;
  int rowBase = bm * 128, cb = bn * 128;

  if (tid < 128) wsqs[tid] = ws[WS_WSQ + cb + tid];

  f32x4 acc[4][4];
  #pragma unroll
  for (int i = 0; i < 4; i++)
    #pragma unroll
    for (int j = 0; j < 4; j++) acc[i][j] = (f32x4){0.f, 0.f, 0.f, 0.f};

  const char* abase = (const char*)(Xp + ((size_t)(bm * 8) << 13));
  const __bf16* wbase = Wp2 + ((size_t)(bn * 8) * 2 + waveN) * 4096;

  // prefetch A kt=0 into buf0
  #pragma unroll
  for (int i = 0; i < 4; i++) {
    int off = wave * 4096 + i * 1024;
    gload_lds16(abase + off + lane * 16, asmem + off);
  }

  for (int kt = 0; kt < 8; kt++) {
    __syncthreads();  // drains A-DMA for buf[kt&1]
    // B fragment loads for this kt (L2-resident Wp2)
    const __bf16* wp = wbase + (size_t)kt * 8192;
    bf16x8 bfr[8];
    #pragma unroll
    for (int f = 0; f < 8; f++) bfr[f] = *(const bf16x8*)(wp + f * 512 + lane * 8);
    // A-DMA for kt+1 into other buffer
    if (kt < 7) {
      const char* as = abase + (size_t)(kt + 1) * 16384;
      int bsel = (kt + 1) & 1;
      #pragma unroll
      for (int i = 0; i < 4; i++) {
        int off = wave * 4096 + i * 1024;
        gload_lds16(as + off + lane * 16, asmem + bsel * 16384 + off);
      }
    }
    const __bf16* Ab = (const __bf16*)(asmem + (kt & 1) * 16384);
    bf16x8 ah[4], al[4];
    #pragma unroll
    for (int mt = 0; mt < 4; mt++) {
      int r = waveM * 64 + mt * 16 + col;
      int ph = quad ^ (r & 7);
      ah[mt] = *(const bf16x8*)&Ab[r * 64 + ph * 8];
      al[mt] = *(const bf16x8*)&Ab[r * 64 + (ph ^ 4) * 8];
    }
    #pragma unroll
    for (int nt = 0; nt < 4; nt++) {
      #pragma unroll
      for (int mt = 0; mt < 4; mt++) {
        acc[mt][nt] = __builtin_amdgcn_mfma_f32_16x16x32_bf16(ah[mt], bfr[nt * 2], acc[mt][nt], 0, 0, 0);
        acc[mt][nt] = __builtin_amdgcn_mfma_f32_16x16x32_bf16(ah[mt], bfr[nt * 2 + 1], acc[mt][nt], 0, 0, 0);
        acc[mt][nt] = __builtin_amdgcn_mfma_f32_16x16x32_bf16(al[mt], bfr[nt * 2], acc[mt][nt], 0, 0, 0);
      }
    }
  }

  // epilogue: per-row (best, 2nd, idx); C layout: row = quad*4 + reg, col = lane&15
  #pragma unroll
  for (int mt = 0; mt < 4; mt++) {
    #pragma unroll
    for (int r = 0; r < 4; r++) {
      float d1 = 3.0e38f, d2 = 3.0e38f;
      int i1 = 0;
      #pragma unroll
      for (int nt = 0; nt < 4; nt++) {
        int lc = waveN * 64 + nt * 16 + col;
        float d = wsqs[lc] - 2.0f * acc[mt][nt][r];
        int g = cb + lc;
        if (d < d1) { d2 = d1; d1 = d; i1 = g; }
        else if (d < d2) d2 = d;
      }
      #pragma unroll
      for (int m = 1; m < 16; m <<= 1) {
        float od1 = __shfl_xor(d1, m);
        int oi1 = __shfl_xor(i1, m);
        float od2 = __shfl_xor(d2, m);
        if (od1 < d1 || (od1 == d1 && oi1 < i1)) {
          d2 = fminf(d1, fminf(d2, od2));
          d1 = od1; i1 = oi1;
        } else {
          d2 = fminf(od1, fminf(d2, od2));
        }
      }
      if (col == 0) {
        int lr = waveM * 64 + mt * 16 + quad * 4 + r;
        d1L[lr * 2 + waveN] = d1;
        d2L[lr * 2 + waveN] = d2;
        i1L[lr * 2 + waveN] = i1;
      }
    }
  }
  __syncthreads();
  if (tid < 128) {
    float a1 = d1L[tid * 2], a2 = d2L[tid * 2];
    int ai = i1L[tid * 2];
    float b1 = d1L[tid * 2 + 1], b2 = d2L[tid * 2 + 1];
    int bi = i1L[tid * 2 + 1];
    float m1, m2; int mi;
    if (b1 < a1 || (b1 == a1 && bi < ai)) { m1 = b1; mi = bi; m2 = fminf(a1, b2); }
    else { m1 = a1; mi = ai; m2 = fminf(b1, a2); }
    int o = bn * NTOT + rowBase + tid;
    ws[WS_CAND1 + o] = m1;
    ws[WS_CAND2 + o] = m2;
    ((int*)ws)[WS_CANDI + o] = mi;
  }
}

// ---------- pass2: merge candidates; idx, commit, flags; fused quant gather ----------
__global__ __launch_bounds__(256) void pass2_kernel(const float* __restrict__ W,
                                                    float* __restrict__ outQ,
                                                    float* __restrict__ outIdx, float* ws) {
  __shared__ int idx_s[256];
  int tid = threadIdx.x;
  int row = blockIdx.x * 256 + tid;
  const float* c1 = ws + WS_CAND1;
  const float* c2 = ws + WS_CAND2;
  const int* ci = (const int*)ws + WS_CANDI;
  float m1 = 3.0e38f, m2 = 3.0e38f;
  int mi = 0;
  #pragma unroll
  for (int b = 0; b < 8; b++) {
    int o = b * NTOT + row;
    float b1 = c1[o], b2 = c2[o];
    int bi = ci[o];
    if (b1 < m1 || (b1 == m1 && bi < mi)) { m2 = fminf(m1, b2); m1 = b1; mi = bi; }
    else { m2 = fminf(m2, b1); }
  }
  outIdx[row] = (float)mi;
  idx_s[tid] = mi;
  int* wsI = (int*)ws;
  if (m2 - m1 < TAU) {
    int p = atomicAdd(&wsI[WS_FLAGCNT], 1);
    wsI[WS_FLAGS + p] = row;
  }
  float partial = ws[WS_XSQ + row] + m1;
  #pragma unroll
  for (int m = 32; m >= 1; m >>= 1) partial += __shfl_xor(partial, m);
  if ((tid & 63) == 0) atomicAdd(&ws[WS_COMMIT], partial);
  __syncthreads();
  int wave = tid >> 6, lane = tid & 63;
  int rowBase = blockIdx.x * 256;
  #pragma unroll 4
  for (int i = 0; i < 64; i++) {
    int rl = wave * 64 + i;
    int ix = idx_s[rl];
    float4 v = ((const float4*)(W + (size_t)ix * DIMS))[lane];
    ((float4*)(outQ + (size_t)(rowBase + rl) * DIMS))[lane] = v;
  }
}

// ---------- decorrelation: 64 blocks x 4 output rows ----------
__global__ __launch_bounds__(256) void cov_kernel(const float* __restrict__ W, float* ws) {
  __shared__ float wi_s[4][KCODES];
  __shared__ float red[4];
  int tid = threadIdx.x;
  int i0 = blockIdx.x * 4;
  int rr = tid >> 2, c = tid & 3;
  #pragma unroll
  for (int b = 0; b < 16; b++) {
    int row = b * 64 + rr;
    wi_s[c][row] = W[(size_t)row * DIMS + i0 + c];
  }
  __syncthreads();
  int j = tid;
  float a0 = 0.f, a1 = 0.f, a2 = 0.f, a3 = 0.f;
  for (int k = 0; k < KCODES; k += 4) {
    #pragma unroll
    for (int u = 0; u < 4; u++) {
      float wj = W[(size_t)(k + u) * DIMS + j];
      a0 = fmaf(wi_s[0][k + u], wj, a0);
      a1 = fmaf(wi_s[1][k + u], wj, a1);
      a2 = fmaf(wi_s[2][k + u], wj, a2);
      a3 = fmaf(wi_s[3][k + u], wj, a3);
    }
  }
  const float inv = 1.0f / 1024.0f;
  float mj = ws[WS_COLSUM + j] * inv;
  float dots[4] = {a0, a1, a2, a3};
  float v = 0.f;
  #pragma unroll
  for (int r = 0; r < 4; r++) {
    float mi = ws[WS_COLSUM + i0 + r] * inv;
    float cc = dots[r] * inv - mi * mj;
    if (i0 + r != j) v = fmaf(cc, cc, v);
  }
  #pragma unroll
  for (int m = 32; m >= 1; m >>= 1) v += __shfl_xor(v, m);
  if ((j & 63) == 0) red[j >> 6] = v;
  __syncthreads();
  if (j == 0) atomicAdd(&ws[WS_DECORR], (red[0] + red[1]) + (red[2] + red[3]));
}

// ---------- f64 refinement of near-tie rows ----------
__global__ __launch_bounds__(256) void refine_kernel(const float* __restrict__ X,
                                                     const float* __restrict__ W,
                                                     float* __restrict__ outQ,
                                                     float* __restrict__ outIdx, float* ws) {
  __shared__ float xs[DIMS];
  __shared__ double dm[256];
  __shared__ int im[256];
  __shared__ int chosen;
  const int* wsI = (const int*)ws;
  int cnt = wsI[WS_FLAGCNT];
  const int* list = wsI + WS_FLAGS;
  int tid = threadIdx.x;
  for (int f = blockIdx.x; f < cnt; f += gridDim.x) {
    int row = list[f];
    __syncthreads();
    if (tid < 64) ((float4*)xs)[tid] = ((const float4*)(X + (size_t)row * DIMS))[tid];
    __syncthreads();
    double bd = 1.0e300;
    int bi = 0;
    for (int jj = 0; jj < 4; jj++) {
      int c = tid + 256 * jj;
      double a0 = 0.0, a1 = 0.0, a2 = 0.0, a3 = 0.0;
      const float* wr = W + (size_t)c * DIMS;
      #pragma unroll 4
      for (int d4 = 0; d4 < 64; d4++) {
        float4 w = ((const float4*)wr)[d4];
        float4 x = ((const float4*)xs)[d4];
        double e0 = (double)x.x - (double)w.x;
        double e1 = (double)x.y - (double)w.y;
        double e2 = (double)x.z - (double)w.z;
        double e3 = (double)x.w - (double)w.w;
        a0 += e0 * e0; a1 += e1 * e1; a2 += e2 * e2; a3 += e3 * e3;
      }
      double s = (a0 + a1) + (a2 + a3);
      if (s < bd) { bd = s; bi = c; }
    }
    dm[tid] = bd; im[tid] = bi;
    __syncthreads();
    for (int st = 128; st >= 1; st >>= 1) {
      if (tid < st) {
        if (dm[tid + st] < dm[tid] || (dm[tid + st] == dm[tid] && im[tid + st] < im[tid])) {
          dm[tid] = dm[tid + st]; im[tid] = im[tid + st];
        }
      }
      __syncthreads();
    }
    if (tid == 0) { chosen = im[0]; outIdx[row] = (float)im[0]; }
    __syncthreads();
    int ix = chosen;
    if (tid < 64)
      ((float4*)(outQ + (size_t)row * DIMS))[tid] = ((const float4*)(W + (size_t)ix * DIMS))[tid];
  }
}

// ---------- scalar losses ----------
__global__ __launch_bounds__(256) void finalize_kernel(const float* __restrict__ U, float* ws,
                                                       float* __restrict__ out) {
  __shared__ float red[256];
  int tid = threadIdx.x;
  float s = 0.f;
  for (int e = tid; e < KCODES; e += 256) s += U[e] + 1e-5f;
  red[tid] = s;
  __syncthreads();
  for (int st = 128; st >= 1; st >>= 1) {
    if (tid < st) red[tid] += red[tid + st];
    __syncthreads();
  }
  float S = red[0];
  __syncthreads();
  float denom = fmaxf(S, 1e-5f * 1024.0f);
  float h = 0.f;
  for (int e = tid; e < KCODES; e += 256) {
    float p = (U[e] + 1e-5f) / denom;
    h += p * logf(p + 1e-5f);
  }
  red[tid] = h;
  __syncthreads();
  for (int st = 128; st >= 1; st >>= 1) {
    if (tid < st) red[tid] += red[tid + st];
    __syncthreads();
  }
  float H = -red[0] / 6.93147180559945f;  // ln(1024)
  __syncthreads();
  float m = ws[WS_COLSUM + tid] * (1.0f / 1024.0f);
  float var = ws[WS_COLSQ + tid] * (1.0f / 1024.0f) - m * m;
  float r = 0.05f - var;
  red[tid] = r > 0.f ? r : 0.f;
  __syncthreads();
  for (int st = 128; st >= 1; st >>= 1) {
    if (tid < st) red[tid] += red[tid + st];
    __syncthreads();
  }
  if (tid == 0) {
    float varloss = 1e-3f * (red[0] / 256.0f);
    float gap = H < 0.5f ? (0.5f - H) : (H > 0.9f ? (H - 0.9f) : 0.0f);
    float entloss = 0.1f * gap * gap;
    float commit = 0.25f * ws[WS_COMMIT] / 8388608.0f;
    float dec = 1e-3f * ws[WS_DECORR] / 65536.0f;
    float* sc = out + OUT_SCAL;
    sc[0] = commit + entloss + varloss + dec;
    sc[1] = commit;
    sc[2] = entloss;
    sc[3] = varloss;
    sc[4] = dec;
    sc[5] = H;
  }
}

extern "C" void kernel_launch(void* const* d_in, const int* in_sizes, int n_in, void* d_out,
                              int out_size, void* d_ws, size_t ws_size, hipStream_t stream) {
  const float* X = (const float*)d_in[0];
  const float* W = (const float*)d_in[1];
  const float* U = (const float*)d_in[2];
  float* out = (float*)d_out;
  float* ws = (float*)d_ws;
  __bf16* Xp = (__bf16*)(out + OUT_Q);       // 33.55 MB, overwritten by pass2's gather
  __bf16* Wp2 = (__bf16*)(ws + WS_WP);       // 1 MB, fragment-ordered

  hipMemsetAsync(d_ws, 0, 2112, stream);
  prep_kernel<<<552, 256, 0, stream>>>(X, W, Xp, Wp2, ws);
  pass1_kernel<<<2048, 256, 0, stream>>>(Xp, Wp2, ws);
  pass2_kernel<<<NTOT / 256, 256, 0, stream>>>(W, out + OUT_Q, out + OUT_IDX, ws);
  cov_kernel<<<64, 256, 0, stream>>>(W, ws);
  refine_kernel<<<512, 256, 0, stream>>>(X, W, out + OUT_Q, out + OUT_IDX, ws);
  finalize_kernel<<<1, 256, 0, stream>>>(U, ws, out);
}

// Round 6
// 237.817 us; speedup vs baseline: 1.0953x; 1.0351x over previous
//
#include <hip/hip_runtime.h>
#include <math.h>

#define DIMS   256
#define KCODES 1024
#define NTOT   32768
#define TAU    4.0e-4f   // 3-term split distance-compare error <~6e-5; 6x margin

typedef __bf16 bf16x8 __attribute__((ext_vector_type(8)));
typedef float  f32x4  __attribute__((ext_vector_type(4)));

// ---- workspace layout (float indices; int views share) ----
#define WS_COMMIT   0          // float atomic
#define WS_FLAGCNT  1          // int atomic
#define WS_DECORR   2          // float atomic
#define WS_COLSUM   16         // float[256]
#define WS_COLSQ    272        // float[256]
#define WS_WSQ      1024       // float[1024]  (atomic-accumulated)
#define WS_XSQ      2048       // float[32768] (atomic-accumulated)
// memset zero region: bytes [0, 139264) covers all of the above
#define WS_FLAGS    34816      // int[32768]
#define WS_CAND1    67584      // float[8*32768]
#define WS_CAND2    329728     // float[8*32768]
#define WS_CANDI    591872     // int[8*32768]
#define WS_WP       854016     // bf16[524288] = 1 MB, fragment-ordered W

// ---- output layout (floats) ----
#define OUT_Q    0
#define OUT_IDX  8388608
#define OUT_SCAL 8421376

// Fragment layout (both Xp and Wp2), bf16 elems:
//   frag(bt, kt, wv, t, hl) base = ((((bt*8+kt)*2+wv)*4+t)*2+hl)*512
//   element (lane = kq*16+lc, e) at base + lane*8 + e
//   holds hi/lo bf16 of src[row = bt*128+wv*64+t*16+lc][k = kt*32+kq*8+e]

// ---------- fused prep ----------
// blocks [0,1024): pack X | [1024,1056): pack W | [1056,1064): colstats | [1064,1192): cov
__global__ __launch_bounds__(256) void prep_kernel(const float* __restrict__ X,
                                                   const float* __restrict__ W,
                                                   __bf16* __restrict__ Xp,
                                                   __bf16* __restrict__ Wp2,
                                                   float* ws) {
  int b = blockIdx.x;
  int tid = threadIdx.x;
  if (b < 1056) {
    bool isW = b >= 1024;
    const float* src = isW ? W : X;
    __bf16* dst = isW ? Wp2 : Xp;
    int sqoff = isW ? WS_WSQ : WS_XSQ;
    int bb = isW ? b - 1024 : b;
    int kt = tid >> 5, mtl = (tid >> 4) & 1, lc = tid & 15;
    int row = bb * 32 + mtl * 16 + lc;
    int bt = row >> 7, c = row & 127;
    int wv = c >> 6, t = (c >> 4) & 3;
    size_t hibase = ((((size_t)(bt * 8 + kt) * 2 + wv) * 4 + t) * 2) * 512;
    const float* s = src + (size_t)row * DIMS + kt * 32;
    float sq = 0.f;
    #pragma unroll
    for (int kq = 0; kq < 4; kq++) {
      float4 u = *(const float4*)(s + kq * 8);
      float4 v = *(const float4*)(s + kq * 8 + 4);
      float f[8] = {u.x, u.y, u.z, u.w, v.x, v.y, v.z, v.w};
      bf16x8 hi, lo;
      #pragma unroll
      for (int e = 0; e < 8; e++) {
        __bf16 h = (__bf16)f[e];
        hi[e] = h;
        lo[e] = (__bf16)(f[e] - (float)h);
        sq = fmaf(f[e], f[e], sq);
      }
      size_t off = (size_t)(kq * 16 + lc) * 8;
      *(bf16x8*)&dst[hibase + off] = hi;
      *(bf16x8*)&dst[hibase + 512 + off] = lo;
    }
    atomicAdd(&ws[sqoff + row], sq);
  } else if (b < 1064) {
    // colstats: 8 blocks x 128 rows
    int d = tid;
    int r0 = (b - 1056) * 128;
    float s = 0.f, sq = 0.f;
    #pragma unroll 8
    for (int k = 0; k < 128; k++) {
      float v = W[(size_t)(r0 + k) * DIMS + d];
      s += v;
      sq = fmaf(v, v, sq);
    }
    atomicAdd(&ws[WS_COLSUM + d], s);
    atomicAdd(&ws[WS_COLSQ + d], sq);
  } else {
    // cov: 128 blocks x 2 columns, self-contained means
    __shared__ float wi_s[2][KCODES];
    __shared__ float red2[256];
    __shared__ float mi_s[2];
    __shared__ float red[4];
    int i0 = (b - 1064) * 2;
    int rr = tid >> 1, cc = tid & 1;
    #pragma unroll
    for (int q = 0; q < 8; q++) {
      int row = q * 128 + rr;
      wi_s[cc][row] = W[(size_t)row * DIMS + i0 + cc];
    }
    __syncthreads();
    float pm = 0.f;
    #pragma unroll
    for (int q = 0; q < 8; q++) pm += wi_s[cc][rr * 8 + q];
    red2[tid] = pm;
    __syncthreads();
    if (tid < 2) {
      float s = 0.f;
      for (int k = tid; k < 256; k += 2) s += red2[k];
      mi_s[tid] = s * (1.0f / 1024.0f);
    }
    int j = tid;
    float a0 = 0.f, a1 = 0.f, sj = 0.f;
    for (int k = 0; k < KCODES; k += 4) {
      #pragma unroll
      for (int u = 0; u < 4; u++) {
        float wj = W[(size_t)(k + u) * DIMS + j];
        a0 = fmaf(wi_s[0][k + u], wj, a0);
        a1 = fmaf(wi_s[1][k + u], wj, a1);
        sj += wj;
      }
    }
    __syncthreads();  // mi_s ready
    const float inv = 1.0f / 1024.0f;
    float mj = sj * inv;
    float v = 0.f;
    float c0 = a0 * inv - mi_s[0] * mj;
    if (i0 != j) v = fmaf(c0, c0, v);
    float c1 = a1 * inv - mi_s[1] * mj;
    if (i0 + 1 != j) v = fmaf(c1, c1, v);
    #pragma unroll
    for (int m = 32; m >= 1; m >>= 1) v += __shfl_xor(v, m);
    if ((j & 63) == 0) red[j >> 6] = v;
    __syncthreads();
    if (j == 0) atomicAdd(&ws[WS_DECORR], (red[0] + red[1]) + (red[2] + red[3]));
  }
}

// ---------- pass1: barrier-free all-register fragment GEMM, 3-term bf16 MFMA ----------
// 1D grid 2048, XCD-swizzled: bm=(l&7)*32+((l>>3)&31), bn=l>>8.
__global__ __launch_bounds__(256, 2) void pass1_kernel(const __bf16* __restrict__ Xp,
                                                       const __bf16* __restrict__ Wp2,
                                                       float* ws) {
  __shared__ float wsqs[128];
  __shared__ float d1L[256];
  __shared__ float d2L[256];
  __shared__ int   i1L[256];

  int tid = threadIdx.x;
  int lane = tid & 63, wave = tid >> 6;
  int wm = wave >> 1, wn = wave & 1;
  int quad = lane >> 4, col = lane & 15;
  int l = blockIdx.x;
  int bm = (l & 7) * 32 + ((l >> 3) & 31);
  int bn = l >> 8;
  int rowBase = bm * 128, cb = bn * 128;

  if (tid < 128) wsqs[tid] = ws[WS_WSQ + cb + tid];

  f32x4 acc[4][4];
  #pragma unroll
  for (int i = 0; i < 4; i++)
    #pragma unroll
    for (int j = 0; j < 4; j++) acc[i][j] = (f32x4){0.f, 0.f, 0.f, 0.f};

  // bf16x8-unit strides: kt=1024, frag t=128, hl=64
  const bf16x8* ab = (const bf16x8*)(Xp + (size_t)bm * 65536 + wm * 4096) + lane;
  const bf16x8* bb = (const bf16x8*)(Wp2 + (size_t)bn * 65536 + wn * 4096) + lane;

  bf16x8 Af[2][8], Bf[2][8];  // [buf][t*2+hl]
  #pragma unroll
  for (int f = 0; f < 4; f++) {
    Af[0][f * 2] = ab[f * 128];
    Af[0][f * 2 + 1] = ab[f * 128 + 64];
    Bf[0][f * 2] = bb[f * 128];
    Bf[0][f * 2 + 1] = bb[f * 128 + 64];
  }
  #pragma unroll
  for (int kt = 0; kt < 8; kt++) {
    const int cur = kt & 1, nxt = cur ^ 1;
    if (kt < 7) {
      const bf16x8* an = ab + (kt + 1) * 1024;
      const bf16x8* bv = bb + (kt + 1) * 1024;
      #pragma unroll
      for (int f = 0; f < 4; f++) {
        Af[nxt][f * 2] = an[f * 128];
        Af[nxt][f * 2 + 1] = an[f * 128 + 64];
        Bf[nxt][f * 2] = bv[f * 128];
        Bf[nxt][f * 2 + 1] = bv[f * 128 + 64];
      }
    }
    #pragma unroll
    for (int nt = 0; nt < 4; nt++) {
      #pragma unroll
      for (int mt = 0; mt < 4; mt++) {
        acc[mt][nt] = __builtin_amdgcn_mfma_f32_16x16x32_bf16(Af[cur][mt * 2], Bf[cur][nt * 2], acc[mt][nt], 0, 0, 0);
        acc[mt][nt] = __builtin_amdgcn_mfma_f32_16x16x32_bf16(Af[cur][mt * 2], Bf[cur][nt * 2 + 1], acc[mt][nt], 0, 0, 0);
        acc[mt][nt] = __builtin_amdgcn_mfma_f32_16x16x32_bf16(Af[cur][mt * 2 + 1], Bf[cur][nt * 2], acc[mt][nt], 0, 0, 0);
      }
    }
  }
  __syncthreads();  // wsqs visibility for all waves

  // epilogue: per-row (best, 2nd, idx); C layout: row = quad*4 + reg, col = lane&15
  #pragma unroll
  for (int mt = 0; mt < 4; mt++) {
    #pragma unroll
    for (int r = 0; r < 4; r++) {
      float d1 = 3.0e38f, d2 = 3.0e38f;
      int i1 = 0;
      #pragma unroll
      for (int nt = 0; nt < 4; nt++) {
        int lc = wn * 64 + nt * 16 + col;
        float d = wsqs[lc] - 2.0f * acc[mt][nt][r];
        int g = cb + lc;
        if (d < d1) { d2 = d1; d1 = d; i1 = g; }
        else if (d < d2) d2 = d;
      }
      #pragma unroll
      for (int m = 1; m < 16; m <<= 1) {
        float od1 = __shfl_xor(d1, m);
        int oi1 = __shfl_xor(i1, m);
        float od2 = __shfl_xor(d2, m);
        if (od1 < d1 || (od1 == d1 && oi1 < i1)) {
          d2 = fminf(d1, fminf(d2, od2));
          d1 = od1; i1 = oi1;
        } else {
          d2 = fminf(od1, fminf(d2, od2));
        }
      }
      if (col == 0) {
        int lr = wm * 64 + mt * 16 + quad * 4 + r;
        d1L[lr * 2 + wn] = d1;
        d2L[lr * 2 + wn] = d2;
        i1L[lr * 2 + wn] = i1;
      }
    }
  }
  __syncthreads();
  if (tid < 128) {
    float a1 = d1L[tid * 2], a2 = d2L[tid * 2];
    int ai = i1L[tid * 2];
    float b1 = d1L[tid * 2 + 1], b2 = d2L[tid * 2 + 1];
    int bi = i1L[tid * 2 + 1];
    float m1, m2; int mi;
    if (b1 < a1 || (b1 == a1 && bi < ai)) { m1 = b1; mi = bi; m2 = fminf(a1, b2); }
    else { m1 = a1; mi = ai; m2 = fminf(b1, a2); }
    int o = bn * NTOT + rowBase + tid;
    ws[WS_CAND1 + o] = m1;
    ws[WS_CAND2 + o] = m2;
    ((int*)ws)[WS_CANDI + o] = mi;
  }
}

// ---------- pass2: merge candidates; idx, commit, flags; fused quant gather ----------
__global__ __launch_bounds__(256) void pass2_kernel(const float* __restrict__ W,
                                                    float* __restrict__ outQ,
                                                    float* __restrict__ outIdx, float* ws) {
  __shared__ int idx_s[256];
  int tid = threadIdx.x;
  int row = blockIdx.x * 256 + tid;
  const float* c1 = ws + WS_CAND1;
  const float* c2 = ws + WS_CAND2;
  const int* ci = (const int*)ws + WS_CANDI;
  float m1 = 3.0e38f, m2 = 3.0e38f;
  int mi = 0;
  #pragma unroll
  for (int b = 0; b < 8; b++) {
    int o = b * NTOT + row;
    float b1 = c1[o], b2 = c2[o];
    int bi = ci[o];
    if (b1 < m1 || (b1 == m1 && bi < mi)) { m2 = fminf(m1, b2); m1 = b1; mi = bi; }
    else { m2 = fminf(m2, b1); }
  }
  outIdx[row] = (float)mi;
  idx_s[tid] = mi;
  int* wsI = (int*)ws;
  if (m2 - m1 < TAU) {
    int p = atomicAdd(&wsI[WS_FLAGCNT], 1);
    wsI[WS_FLAGS + p] = row;
  }
  float partial = ws[WS_XSQ + row] + m1;
  #pragma unroll
  for (int m = 32; m >= 1; m >>= 1) partial += __shfl_xor(partial, m);
  if ((tid & 63) == 0) atomicAdd(&ws[WS_COMMIT], partial);
  __syncthreads();
  int wave = tid >> 6, lane = tid & 63;
  int rowBase = blockIdx.x * 256;
  #pragma unroll 4
  for (int i = 0; i < 64; i++) {
    int rl = wave * 64 + i;
    int ix = idx_s[rl];
    float4 v = ((const float4*)(W + (size_t)ix * DIMS))[lane];
    ((float4*)(outQ + (size_t)(rowBase + rl) * DIMS))[lane] = v;
  }
}

// ---------- f64 refinement (blocks 0..511) + fused scalar finalize (block 512) ----------
__global__ __launch_bounds__(256) void refine_kernel(const float* __restrict__ X,
                                                     const float* __restrict__ W,
                                                     float* __restrict__ outQ,
                                                     float* __restrict__ outIdx, float* ws,
                                                     const float* __restrict__ U,
                                                     float* __restrict__ out) {
  __shared__ float xs[DIMS];
  __shared__ double dm[256];
  __shared__ int im[256];
  __shared__ int chosen;
  int tid = threadIdx.x;
  if (blockIdx.x == 512) {
    // ---- finalize ----
    __shared__ float red[256];
    float s = 0.f;
    for (int e = tid; e < KCODES; e += 256) s += U[e] + 1e-5f;
    red[tid] = s;
    __syncthreads();
    for (int st = 128; st >= 1; st >>= 1) {
      if (tid < st) red[tid] += red[tid + st];
      __syncthreads();
    }
    float S = red[0];
    __syncthreads();
    float denom = fmaxf(S, 1e-5f * 1024.0f);
    float h = 0.f;
    for (int e = tid; e < KCODES; e += 256) {
      float p = (U[e] + 1e-5f) / denom;
      h += p * logf(p + 1e-5f);
    }
    red[tid] = h;
    __syncthreads();
    for (int st = 128; st >= 1; st >>= 1) {
      if (tid < st) red[tid] += red[tid + st];
      __syncthreads();
    }
    float H = -red[0] / 6.93147180559945f;  // ln(1024)
    __syncthreads();
    float m = ws[WS_COLSUM + tid] * (1.0f / 1024.0f);
    float var = ws[WS_COLSQ + tid] * (1.0f / 1024.0f) - m * m;
    float r = 0.05f - var;
    red[tid] = r > 0.f ? r : 0.f;
    __syncthreads();
    for (int st = 128; st >= 1; st >>= 1) {
      if (tid < st) red[tid] += red[tid + st];
      __syncthreads();
    }
    if (tid == 0) {
      float varloss = 1e-3f * (red[0] / 256.0f);
      float gap = H < 0.5f ? (0.5f - H) : (H > 0.9f ? (H - 0.9f) : 0.0f);
      float entloss = 0.1f * gap * gap;
      float commit = 0.25f * ws[WS_COMMIT] / 8388608.0f;
      float dec = 1e-3f * ws[WS_DECORR] / 65536.0f;
      float* sc = out + OUT_SCAL;
      sc[0] = commit + entloss + varloss + dec;
      sc[1] = commit;
      sc[2] = entloss;
      sc[3] = varloss;
      sc[4] = dec;
      sc[5] = H;
    }
    return;
  }
  const int* wsI = (const int*)ws;
  int cnt = wsI[WS_FLAGCNT];
  const int* list = wsI + WS_FLAGS;
  for (int f = blockIdx.x; f < cnt; f += 512) {
    int row = list[f];
    __syncthreads();
    if (tid < 64) ((float4*)xs)[tid] = ((const float4*)(X + (size_t)row * DIMS))[tid];
    __syncthreads();
    double bd = 1.0e300;
    int bi = 0;
    for (int jj = 0; jj < 4; jj++) {
      int c = tid + 256 * jj;
      double a0 = 0.0, a1 = 0.0, a2 = 0.0, a3 = 0.0;
      const float* wr = W + (size_t)c * DIMS;
      #pragma unroll 4
      for (int d4 = 0; d4 < 64; d4++) {
        float4 w = ((const float4*)wr)[d4];
        float4 x = ((const float4*)xs)[d4];
        double e0 = (double)x.x - (double)w.x;
        double e1 = (double)x.y - (double)w.y;
        double e2 = (double)x.z - (double)w.z;
        double e3 = (double)x.w - (double)w.w;
        a0 += e0 * e0; a1 += e1 * e1; a2 += e2 * e2; a3 += e3 * e3;
      }
      double s = (a0 + a1) + (a2 + a3);
      if (s < bd) { bd = s; bi = c; }
    }
    dm[tid] = bd; im[tid] = bi;
    __syncthreads();
    for (int st = 128; st >= 1; st >>= 1) {
      if (tid < st) {
        if (dm[tid + st] < dm[tid] || (dm[tid + st] == dm[tid] && im[tid + st] < im[tid])) {
          dm[tid] = dm[tid + st]; im[tid] = im[tid + st];
        }
      }
      __syncthreads();
    }
    if (tid == 0) { chosen = im[0]; outIdx[row] = (float)im[0]; }
    __syncthreads();
    int ix = chosen;
    if (tid < 64)
      ((float4*)(outQ + (size_t)row * DIMS))[tid] = ((const float4*)(W + (size_t)ix * DIMS))[tid];
  }
}

extern "C" void kernel_launch(void* const* d_in, const int* in_sizes, int n_in, void* d_out,
                              int out_size, void* d_ws, size_t ws_size, hipStream_t stream) {
  const float* X = (const float*)d_in[0];
  const float* W = (const float*)d_in[1];
  const float* U = (const float*)d_in[2];
  float* out = (float*)d_out;
  float* ws = (float*)d_ws;
  __bf16* Xp = (__bf16*)(out + OUT_Q);       // 33.55 MB, overwritten by pass2's gather
  __bf16* Wp2 = (__bf16*)(ws + WS_WP);       // 1 MB, fragment-ordered

  hipMemsetAsync(d_ws, 0, 139264, stream);
  prep_kernel<<<1192, 256, 0, stream>>>(X, W, Xp, Wp2, ws);
  pass1_kernel<<<2048, 256, 0, stream>>>(Xp, Wp2, ws);
  pass2_kernel<<<NTOT / 256, 256, 0, stream>>>(W, out + OUT_Q, out + OUT_IDX, ws);
  refine_kernel<<<513, 256, 0, stream>>>(X, W, out + OUT_Q, out + OUT_IDX, ws, U, out);
}